// Round 7
// baseline (367.243 us; speedup 1.0000x reference)
//
#include <hip/hip_runtime.h>
#include <cstdint>

#define T_TOK 512
#define H_DIM 2048
#define I_DIM 1408
#define N_EXP 16

typedef __attribute__((ext_vector_type(8))) _Float16 f16x8;
typedef __attribute__((ext_vector_type(4))) _Float16 f16x4;
typedef __attribute__((ext_vector_type(4))) float f32x4;

__device__ __forceinline__ f16x4 cvtf4(f32x4 v) {
  f16x4 r;
  r[0] = (_Float16)v[0]; r[1] = (_Float16)v[1];
  r[2] = (_Float16)v[2]; r[3] = (_Float16)v[3];
  return r;
}

// ---------------- kernel 1: routing + x -> fp16 ----------------
__global__ __launch_bounds__(256) void route_kernel(
    const float* __restrict__ x, const float* __restrict__ gw,
    const float* __restrict__ bias, float* __restrict__ coef,
    _Float16* __restrict__ xb) {
  const int t = blockIdx.x;
  const int tid = threadIdx.x;
  const float* xt = x + (size_t)t * H_DIM;
  _Float16* xbt = xb + (size_t)t * H_DIM;

  float part[N_EXP];
#pragma unroll
  for (int e = 0; e < N_EXP; ++e) part[e] = 0.f;
  for (int j = tid; j < H_DIM; j += 256) {
    float xv = xt[j];
    xbt[j] = (_Float16)xv;
#pragma unroll
    for (int e = 0; e < N_EXP; ++e) part[e] += xv * gw[e * H_DIM + j];
  }
#pragma unroll
  for (int e = 0; e < N_EXP; ++e) {
#pragma unroll
    for (int off = 32; off > 0; off >>= 1) part[e] += __shfl_down(part[e], off);
  }
  __shared__ float red[4][N_EXP];
  const int lane = tid & 63, w = tid >> 6;
  if (lane == 0) {
#pragma unroll
    for (int e = 0; e < N_EXP; ++e) red[w][e] = part[e];
  }
  __syncthreads();
  if (tid == 0) {
    float s[16], sf[16];
    for (int e = 0; e < 16; ++e) {
      float lg = red[0][e] + red[1][e] + red[2][e] + red[3][e];
      s[e] = 1.f / (1.f + expf(-lg));
      sf[e] = s[e] + bias[e];
    }
    float gsc[4];
    for (int g = 0; g < 4; ++g) {
      float m1 = -1e30f, m2 = -1e30f;
      for (int j = 0; j < 4; ++j) {
        float v = sf[g * 4 + j];
        if (v > m1) { m2 = m1; m1 = v; }
        else if (v > m2) { m2 = v; }
      }
      gsc[g] = m1 + m2;
    }
    int g1 = 0;
    for (int g = 1; g < 4; ++g) if (gsc[g] > gsc[g1]) g1 = g;
    int g2 = -1;
    for (int g = 0; g < 4; ++g) {
      if (g == g1) continue;
      if (g2 < 0 || gsc[g] > gsc[g2]) g2 = g;
    }
    bool gok[4];
    for (int g = 0; g < 4; ++g) gok[g] = (g == g1) || (g == g2);
    bool sel[16];
    for (int e = 0; e < 16; ++e) sel[e] = false;
    float wsum = 0.f;
    for (int k = 0; k < 6; ++k) {
      int best = -1; float bv = 0.f;
      for (int e2 = 0; e2 < 16; ++e2) {
        if (!gok[e2 >> 2] || sel[e2]) continue;
        if (best < 0 || sf[e2] > bv) { bv = sf[e2]; best = e2; }
      }
      sel[best] = true;
      wsum += s[best];
    }
    float inv = 2.5f / wsum;
    for (int e = 0; e < 16; ++e) coef[t * N_EXP + e] = sel[e] ? s[e] * inv : 0.f;
  }
}

// ---------------- kernel 2: per-expert token lists ----------------
__global__ __launch_bounds__(512) void build_lists_kernel(
    const float* __restrict__ coef, int* __restrict__ counts,
    int* __restrict__ lists) {
  const int e = blockIdx.x;
  const int t = threadIdx.x;
  const bool flag = coef[t * N_EXP + e] != 0.f;
  const unsigned long long m = __ballot(flag);
  const int lane = t & 63, w = t >> 6;
  __shared__ int wcnt[8], woff[8];
  if (lane == 0) wcnt[w] = __popcll(m);
  __syncthreads();
  if (t == 0) {
    int a = 0;
    for (int i = 0; i < 8; ++i) { woff[i] = a; a += wcnt[i]; }
    counts[e] = a;
  }
  __syncthreads();
  if (flag) {
    int pos = woff[w] + __popcll(m & ((1ull << lane) - 1ull));
    lists[e * T_TOK + pos] = t;
  }
}

// ---------------- kernel 3: gate+up, wave-autonomous pipelined GEMM ---------
// Wave tile 64x32 (both matrices). NO barriers, NO global_load_lds.
// B: coalesced f32x4 (8 lanes/row of 128B), 4-slot reg lead, cvt->fp16 ->
//    wave-private swizzled LDS ring2. A: direct-to-reg frag gathers (L2-hot).
// work: block=(e, rb, strip-quad); wave w -> strip sq*4+w.
__global__ __launch_bounds__(256, 2) void gate_up_kernel(
    const _Float16* __restrict__ xb, const float* __restrict__ wg,
    const float* __restrict__ wu, const int* __restrict__ counts,
    const int* __restrict__ lists, _Float16* __restrict__ hbuf) {
  __shared__ _Float16 Bsh[4][2][2][32 * 32];   // [wave][buf][g,u][2KB] = 32 KB
  const int tid = threadIdx.x;
  const int lane = tid & 63;
  const int w = tid >> 6;
  const int bx = blockIdx.x;                   // 0..1407
  const int wb = (bx & 7) * 176 + (bx >> 3);   // XCD-chunked
  const int e = wb / 88;
  const int r2 = wb % 88;
  const int rb = r2 / 11;
  const int sq = r2 % 11;
  const int ne = counts[e];
  if (rb * 64 >= ne) return;
  const int strip = sq * 4 + w;                // 0..43
  const int col0 = strip * 32;

  // A fragment gather pointers (4 m-blocks of 16 token-rows)
  const int* lst = lists + e * T_TOK;
  const _Float16* ap[4];
#pragma unroll
  for (int m = 0; m < 4; ++m) {
    int r = rb * 64 + m * 16 + (lane & 15);
    ap[m] = xb + (size_t)lst[min(r, ne - 1)] * H_DIM + (lane >> 4) * 8;
  }
  // B coalesced pointers: instr i covers rows i*8..i*8+8, lane= row(l>>3), 16B chunk(l&7)
  const float* gp[4];
  const float* up[4];
#pragma unroll
  for (int i = 0; i < 4; ++i) {
    size_t off = ((size_t)e * I_DIM + col0 + i * 8 + (lane >> 3)) * H_DIM + (lane & 7) * 4;
    gp[i] = wg + off;
    up[i] = wu + off;
  }
  // LDS write slots for this lane
  const int wrow = lane >> 3;                  // +i*8
  const int wkc = lane & 7;                    // 8B fp16 chunk

  f32x4 accg[4][2], accu[4][2];
  const f32x4 zz = {0.f, 0.f, 0.f, 0.f};
#pragma unroll
  for (int m = 0; m < 4; ++m)
#pragma unroll
    for (int n = 0; n < 2; ++n) { accg[m][n] = zz; accu[m][n] = zz; }

  auto loadB = [&](f32x4 (&g)[4], f32x4 (&u)[4], int kt) {
    const int k0 = kt * 32;
#pragma unroll
    for (int i = 0; i < 4; ++i) {
      g[i] = *(const f32x4*)(gp[i] + k0);
      u[i] = *(const f32x4*)(up[i] + k0);
    }
  };
  auto loadA = [&](f16x8 (&a)[4], int kt) {
    const int k0 = kt * 32;
#pragma unroll
    for (int m = 0; m < 4; ++m) a[m] = *(const f16x8*)(ap[m] + k0);
  };
  auto writeB = [&](int buf, f32x4 (&g)[4], f32x4 (&u)[4]) {
#pragma unroll
    for (int i = 0; i < 4; ++i) {
      int row = i * 8 + wrow;
      int off = row * 64 + (((wkc >> 1) ^ ((row >> 1) & 3)) * 16) + (wkc & 1) * 8;
      *(f16x4*)((char*)&Bsh[w][buf][0][0] + off) = cvtf4(g[i]);
      *(f16x4*)((char*)&Bsh[w][buf][1][0] + off) = cvtf4(u[i]);
    }
  };
  auto comp = [&](int buf, f16x8 (&a)[4]) {
    f16x8 bg[2], bu[2];
#pragma unroll
    for (int n = 0; n < 2; ++n) {
      int rr = n * 16 + (lane & 15);
      int off = rr * 64 + ((((lane >> 4) ^ ((rr >> 1) & 3))) * 16);
      bg[n] = *(const f16x8*)((const char*)&Bsh[w][buf][0][0] + off);
      bu[n] = *(const f16x8*)((const char*)&Bsh[w][buf][1][0] + off);
    }
#pragma unroll
    for (int m = 0; m < 4; ++m)
#pragma unroll
      for (int n = 0; n < 2; ++n) {
        accg[m][n] = __builtin_amdgcn_mfma_f32_16x16x32_f16(a[m], bg[n], accg[m][n], 0, 0, 0);
        accu[m][n] = __builtin_amdgcn_mfma_f32_16x16x32_f16(a[m], bu[n], accu[m][n], 0, 0, 0);
      }
  };

  const int NK = H_DIM / 32;   // 64
  f32x4 g0[4], u0[4], g1[4], u1[4];
  f16x8 a0[4], a1[4];

  loadB(g0, u0, 0); loadA(a0, 0);
  loadB(g1, u1, 1); loadA(a1, 1);
  writeB(0, g0, u0);
  loadB(g0, u0, 2);
  writeB(1, g1, u1);
  loadB(g1, u1, 3);

  // steady state entering pair kt: buf0=B(kt), buf1=B(kt+1), g0=B(kt+2),
  // g1=B(kt+3), a0=A(kt), a1=A(kt+1)
#pragma unroll 1
  for (int kt = 0; kt < NK; kt += 2) {
    comp(0, a0);
    if (kt + 2 < NK) {
      loadA(a0, kt + 2);
      writeB(0, g0, u0);
      if (kt + 4 < NK) loadB(g0, u0, kt + 4);
    }
    comp(1, a1);
    if (kt + 3 < NK) {
      loadA(a1, kt + 3);
      writeB(1, g1, u1);
      if (kt + 5 < NK) loadB(g1, u1, kt + 5);
    }
  }

  // epilogue: silu(g)*u -> fp16 h
  _Float16* hb = hbuf + (size_t)e * T_TOK * I_DIM;
#pragma unroll
  for (int m = 0; m < 4; ++m) {
#pragma unroll
    for (int j = 0; j < 4; ++j) {
      int r = rb * 64 + m * 16 + (lane >> 4) * 4 + j;
      if (r < ne) {
#pragma unroll
        for (int n = 0; n < 2; ++n) {
          int cc = col0 + n * 16 + (lane & 15);
          float g = accg[m][n][j];
          float u = accu[m][n][j];
          float hv = (g / (1.f + __expf(-g))) * u;
          hb[(size_t)r * I_DIM + cc] = (_Float16)hv;
        }
      }
    }
  }
}

// ---------------- kernel 4: down GEMM, wave-autonomous + scatter-add --------
__global__ __launch_bounds__(256, 3) void down_kernel(
    const _Float16* __restrict__ hbuf, const float* __restrict__ wd,
    const int* __restrict__ counts, const int* __restrict__ lists,
    const float* __restrict__ coef, float* __restrict__ out) {
  __shared__ _Float16 Dsh[4][2][32 * 32];      // [wave][buf][2KB] = 16 KB
  const int tid = threadIdx.x;
  const int lane = tid & 63;
  const int w = tid >> 6;
  const int bx = blockIdx.x;                   // 0..2047
  const int wb = (bx & 7) * 256 + (bx >> 3);
  const int e = wb / 128;
  const int r2 = wb % 128;
  const int rb = r2 / 16;
  const int sq = r2 % 16;
  const int ne = counts[e];
  if (rb * 64 >= ne) return;
  const int strip = sq * 4 + w;                // 0..63
  const int col0 = strip * 32;

  const _Float16* hb = hbuf + (size_t)e * T_TOK * I_DIM;
  const _Float16* ap[4];
#pragma unroll
  for (int m = 0; m < 4; ++m) {
    int r = rb * 64 + m * 16 + (lane & 15);    // < 512 always
    ap[m] = hb + (size_t)r * I_DIM + (lane >> 4) * 8;
  }
  const float* bp[4];
#pragma unroll
  for (int i = 0; i < 4; ++i)
    bp[i] = wd + ((size_t)e * H_DIM + col0 + i * 8 + (lane >> 3)) * I_DIM + (lane & 7) * 4;
  const int wrow = lane >> 3;
  const int wkc = lane & 7;

  f32x4 acc[4][2];
  const f32x4 zz = {0.f, 0.f, 0.f, 0.f};
#pragma unroll
  for (int m = 0; m < 4; ++m)
#pragma unroll
    for (int n = 0; n < 2; ++n) acc[m][n] = zz;

  auto loadB = [&](f32x4 (&b)[4], int kt) {
    const int k0 = kt * 32;
#pragma unroll
    for (int i = 0; i < 4; ++i) b[i] = *(const f32x4*)(bp[i] + k0);
  };
  auto loadA = [&](f16x8 (&a)[4], int kt) {
    const int k0 = kt * 32;
#pragma unroll
    for (int m = 0; m < 4; ++m) a[m] = *(const f16x8*)(ap[m] + k0);
  };
  auto writeB = [&](int buf, f32x4 (&b)[4]) {
#pragma unroll
    for (int i = 0; i < 4; ++i) {
      int row = i * 8 + wrow;
      int off = row * 64 + (((wkc >> 1) ^ ((row >> 1) & 3)) * 16) + (wkc & 1) * 8;
      *(f16x4*)((char*)&Dsh[w][buf][0] + off) = cvtf4(b[i]);
    }
  };
  auto comp = [&](int buf, f16x8 (&a)[4]) {
    f16x8 bf[2];
#pragma unroll
    for (int n = 0; n < 2; ++n) {
      int rr = n * 16 + (lane & 15);
      int off = rr * 64 + ((((lane >> 4) ^ ((rr >> 1) & 3))) * 16);
      bf[n] = *(const f16x8*)((const char*)&Dsh[w][buf][0] + off);
    }
#pragma unroll
    for (int m = 0; m < 4; ++m)
#pragma unroll
      for (int n = 0; n < 2; ++n)
        acc[m][n] = __builtin_amdgcn_mfma_f32_16x16x32_f16(a[m], bf[n], acc[m][n], 0, 0, 0);
  };

  const int NK = I_DIM / 32;   // 44
  f32x4 b0[4], b1[4];
  f16x8 a0[4], a1[4];

  loadB(b0, 0); loadA(a0, 0);
  loadB(b1, 1); loadA(a1, 1);
  writeB(0, b0);
  loadB(b0, 2);
  writeB(1, b1);
  loadB(b1, 3);

#pragma unroll 1
  for (int kt = 0; kt < NK; kt += 2) {
    comp(0, a0);
    if (kt + 2 < NK) {
      loadA(a0, kt + 2);
      writeB(0, b0);
      if (kt + 4 < NK) loadB(b0, kt + 4);
    }
    comp(1, a1);
    if (kt + 3 < NK) {
      loadA(a1, kt + 3);
      writeB(1, b1);
      if (kt + 5 < NK) loadB(b1, kt + 5);
    }
  }

#pragma unroll
  for (int m = 0; m < 4; ++m) {
#pragma unroll
    for (int j = 0; j < 4; ++j) {
      int r = rb * 64 + m * 16 + (lane >> 4) * 4 + j;
      if (r < ne) {
        int tok = lists[e * T_TOK + r];
        float c = coef[tok * N_EXP + e];
#pragma unroll
        for (int n = 0; n < 2; ++n) {
          int cc = col0 + n * 16 + (lane & 15);
          atomicAdd(&out[(size_t)tok * H_DIM + cc], acc[m][n][j] * c);
        }
      }
    }
  }
}

// ---------------- launch ----------------
extern "C" void kernel_launch(void* const* d_in, const int* in_sizes, int n_in,
                              void* d_out, int out_size, void* d_ws, size_t ws_size,
                              hipStream_t stream) {
  const float* x  = (const float*)d_in[0];
  const float* gw = (const float*)d_in[1];
  const float* cb = (const float*)d_in[2];
  const float* wg = (const float*)d_in[3];
  const float* wu = (const float*)d_in[4];
  const float* wd = (const float*)d_in[5];
  float* out = (float*)d_out;
  char* ws = (char*)d_ws;

  float* coef   = (float*)(ws);                    // 512*16*4 = 32768
  int*   counts = (int*)(ws + 32768);              // 64 B
  int*   lists  = (int*)(ws + 33024);              // 16*512*4 = 32768
  _Float16* xb  = (_Float16*)(ws + 66048);         // 512*2048*2 = 2 MiB
  _Float16* hbuf= (_Float16*)(ws + 66048 + 2097152 + 256); // 16*512*1408*2 = 23 MiB

  hipMemsetAsync(d_out, 0, (size_t)out_size * sizeof(float), stream);

  route_kernel<<<T_TOK, 256, 0, stream>>>(x, gw, cb, coef, xb);
  build_lists_kernel<<<N_EXP, 512, 0, stream>>>(coef, counts, lists);
  gate_up_kernel<<<1408, 256, 0, stream>>>(xb, wg, wu, counts, lists, hbuf);
  down_kernel<<<2048, 256, 0, stream>>>(hbuf, wd, counts, lists, coef, out);
}